// Round 7
// baseline (1112.988 us; speedup 1.0000x reference)
//
#include <hip/hip_runtime.h>
#include <hip/hip_bf16.h>

// Problem constants
#define BB   4
#define SS   2048
#define HID_ 768
#define NH   12
#define HD_  64
#define MR   8192          // B*S
#define XELEMS 6291456     // 8192*768

typedef __attribute__((ext_vector_type(8))) short short8;
typedef __attribute__((ext_vector_type(4))) float floatx4;
typedef __attribute__((ext_vector_type(2))) unsigned int uintx2;

__device__ __forceinline__ unsigned short f2bf(float f) {
  union { float f; unsigned int u; } x; x.f = f;
  unsigned int r = x.u + 0x7fffu + ((x.u >> 16) & 1u);  // RNE
  return (unsigned short)(r >> 16);
}

__device__ __forceinline__ float bf2f(unsigned short u) {
  return __builtin_bit_cast(float, (unsigned int)u << 16);
}

// packed f32x2 -> bf16x2 (RNE), 1 VALU instr for 2 values
__device__ __forceinline__ unsigned int cvt_pk_bf16(float lo, float hi) {
  unsigned int r;
  asm("v_cvt_pk_bf16_f32 %0, %1, %2" : "=v"(r) : "v"(lo), "v"(hi));
  return r;
}

// concat two 4-key b64 pieces into one 8-slot MFMA operand (regs j0..3 | j4..7)
__device__ __forceinline__ short8 cat64(uintx2 a, uintx2 b) {
  union { unsigned int u[4]; short8 s; } x;
  x.u[0] = a.x; x.u[1] = a.y; x.u[2] = b.x; x.u[3] = b.y;
  return x.s;
}

// async global -> LDS, 16 B per lane; lds base is wave-uniform, HW adds lane*16
__device__ __forceinline__ void gload_lds16(const unsigned short* g, unsigned short* l) {
  __builtin_amdgcn_global_load_lds(
      (const __attribute__((address_space(1))) unsigned int*)g,
      (__attribute__((address_space(3))) unsigned int*)l, 16, 0, 0);
}

// ---------------------------------------------------------------- cast fp32 -> bf16 (both streams)
struct CastArgs { const float* src[2]; unsigned short* dst[2]; };

__global__ __launch_bounds__(256)
void cast_kernel(CastArgs a) {
  const int z = blockIdx.y;
  int i = (blockIdx.x * 256 + threadIdx.x) * 4;
  float4 v = *(const float4*)(a.src[z] + i);
  ushort4 o;
  o.x = f2bf(v.x); o.y = f2bf(v.y); o.z = f2bf(v.z); o.w = f2bf(v.w);
  *(ushort4*)(a.dst[z] + i) = o;
}

// ---------------------------------------------------------------- weight transpose+cast
// in: W[k][n] fp32 (768x768), out: Wt[n][k] bf16
struct WArgs { const float* src[8]; unsigned short* dst[8]; };

__global__ __launch_bounds__(256)
void wcast_kernel(WArgs args) {
  __shared__ float tile[32][33];
  const int w = blockIdx.z;
  const float* __restrict__ src = args.src[w];
  unsigned short* __restrict__ dst = args.dst[w];
  const int n0 = blockIdx.x * 32, k0 = blockIdx.y * 32;
  const int tx = threadIdx.x & 31, ty = threadIdx.x >> 5;  // 32 x 8
  #pragma unroll
  for (int i = 0; i < 4; ++i)
    tile[ty + 8 * i][tx] = src[(size_t)(k0 + ty + 8 * i) * HID_ + n0 + tx];
  __syncthreads();
  #pragma unroll
  for (int i = 0; i < 4; ++i)
    dst[(size_t)(n0 + ty + 8 * i) * HID_ + k0 + tx] = f2bf(tile[tx][ty + 8 * i]);
}

// ---------------------------------------------------------------- GEMM: C = A[M,768] * Bt[N,768]^T
// ROUND-3-EXACT single-buffered loop (verified passing): per K-step
// { stage cur ; __syncthreads ; ds_read+MFMA ; __syncthreads }.
// FROZEN: dbuf variants (r4 counted vmcnt / r5 drain) both failed — do not
// re-pipeline this loop without a new verification path.
// MODE 0: bf16 out; per-z tmode 0 = row-major [tok][hid], 2 = V-transposed [b,h,d,s]
// MODE 1: bf16 out = acc + bias + resid  (pre-LN activation, read by ln_kernel)
struct GemmArgs {
  const unsigned short* A[6];
  const unsigned short* Bt[6];
  const float* bias[6];
  const float* resid[6];
  unsigned short* outb[6];
  int tmode[6];
};

template <int MODE>
__global__ __launch_bounds__(256)
void gemm_kernel(GemmArgs args) {
  const int z = blockIdx.z;
  const unsigned short* __restrict__ A  = args.A[z];
  const unsigned short* __restrict__ Bt = args.Bt[z];
  const int m0 = blockIdx.x * 128;
  const int n0 = blockIdx.y * 128;

  __shared__ __align__(16) unsigned short a_sh[128 * 32];  // 8 KB, pitch 32
  __shared__ __align__(16) unsigned short b_sh[128 * 32];

  const int tid  = threadIdx.x;
  const int lane = tid & 63;
  const int wave = tid >> 6;
  const int wm = (wave & 1) * 64;
  const int wn = (wave >> 1) * 64;
  const int l15 = lane & 15;
  const int ko  = lane >> 4;     // 0..3

  floatx4 acc[4][4];
  #pragma unroll
  for (int mt = 0; mt < 4; ++mt)
    #pragma unroll
    for (int nt = 0; nt < 4; ++nt) {
      floatx4 zz = {0.f, 0.f, 0.f, 0.f};
      acc[mt][nt] = zz;
    }

  // staging: 8 chunks of 16 rows x 32 cols; wave handles chunks {2w, 2w+1}
  const int ch0 = wave * 2;
  size_t aoff[2], boff[2];
  unsigned short *adst[2], *bdst[2];
  #pragma unroll
  for (int j = 0; j < 2; ++j) {
    const int ch = ch0 + j;
    const int row = ch * 16 + (lane >> 2);
    const int col = (lane & 3) * 8;
    aoff[j] = (size_t)(m0 + row) * 768 + col;
    boff[j] = (size_t)(n0 + row) * 768 + col;
    adst[j] = a_sh + ch * 512 + lane * 8;
    bdst[j] = b_sh + ch * 512 + lane * 8;
  }

  for (int k0 = 0; k0 < 768; k0 += 32) {
    #pragma unroll
    for (int j = 0; j < 2; ++j) {
      gload_lds16(A  + aoff[j] + k0, adst[j]);
      gload_lds16(Bt + boff[j] + k0, bdst[j]);
    }
    __syncthreads();
    short8 af[4], bfr[4];
    #pragma unroll
    for (int t = 0; t < 4; ++t) {
      af[t]  = *(const short8*)(a_sh + (wm + t * 16 + l15) * 32 + ko * 8);
      bfr[t] = *(const short8*)(b_sh + (wn + t * 16 + l15) * 32 + ko * 8);
    }
    #pragma unroll
    for (int mt = 0; mt < 4; ++mt)
      #pragma unroll
      for (int nt = 0; nt < 4; ++nt)
        acc[mt][nt] = __builtin_amdgcn_mfma_f32_16x16x32_bf16(af[mt], bfr[nt], acc[mt][nt], 0, 0, 0);
    __syncthreads();
  }

  // epilogue. C/D layout: row = (lane>>4)*4 + r, col = lane&15
  if (MODE == 0) {
    const float* __restrict__ bias = args.bias[z];
    unsigned short* __restrict__ out = args.outb[z];
    if (args.tmode[z] == 0) {
      #pragma unroll
      for (int mt = 0; mt < 4; ++mt) {
        const int gm = m0 + wm + mt * 16 + ko * 4;
        #pragma unroll
        for (int nt = 0; nt < 4; ++nt) {
          const int gn = n0 + wn + nt * 16 + l15;
          const float bv = bias[gn];
          #pragma unroll
          for (int r = 0; r < 4; ++r)
            out[(size_t)(gm + r) * 768 + gn] = f2bf(acc[mt][nt][r] + bv);
        }
      }
    } else {
      // V: write transposed [b][h][d][s]; r walks consecutive s -> ushort4 stores
      #pragma unroll
      for (int mt = 0; mt < 4; ++mt) {
        const int gm = m0 + wm + mt * 16 + ko * 4;
        const int bb_ = gm >> 11;
        const int s   = gm & 2047;
        #pragma unroll
        for (int nt = 0; nt < 4; ++nt) {
          const int gn = n0 + wn + nt * 16 + l15;
          const float bv = bias[gn];
          const int h = gn >> 6, d = gn & 63;
          ushort4 o4;
          o4.x = f2bf(acc[mt][nt][0] + bv);
          o4.y = f2bf(acc[mt][nt][1] + bv);
          o4.z = f2bf(acc[mt][nt][2] + bv);
          o4.w = f2bf(acc[mt][nt][3] + bv);
          *(ushort4*)(out + ((size_t)((bb_ * 12 + h) * 64 + d)) * 2048 + s) = o4;
        }
      }
    }
  } else {
    // MODE 1: pre-LN activation = acc + bias + resid, stored bf16
    const float* __restrict__ bias  = args.bias[z];
    const float* __restrict__ resid = args.resid[z];
    unsigned short* __restrict__ out = args.outb[z];
    #pragma unroll
    for (int mt = 0; mt < 4; ++mt) {
      const int gm = m0 + wm + mt * 16 + ko * 4;
      #pragma unroll
      for (int nt = 0; nt < 4; ++nt) {
        const int gn = n0 + wn + nt * 16 + l15;
        const float bv = bias[gn];
        #pragma unroll
        for (int r = 0; r < 4; ++r)
          out[(size_t)(gm + r) * 768 + gn] =
              f2bf(acc[mt][nt][r] + bv + resid[(size_t)(gm + r) * 768 + gn]);
      }
    }
  }
}

// ---------------------------------------------------------------- flash attention
// grid: (S/256, H, B*2) = 768 blocks = exactly 3/CU.  z = b*2 + w.
// 64 q-rows PER WAVE.  K-tile 64 in 32-key halves.  Double-buffered K/V
// staging via global_load_lds.  Swapped QK^T -> S^T; PV fully in-register
// with K=32 MFMA (concat'd V/P pieces, identical k-slot perm).
// LDS block placement pos = kb ^ ((row>>1)&3).  s_setprio(1) around compute.
// THIS ROUND: msk_sh deleted (was pushing LDS_Block_Size to 53248 -> only 2
// blocks/CU resident, occupancy 18%).  Mask returns to the round-1-proven
// register prefetch: per tile issue 4 float4 mask loads FIRST, then the 4
// staging loads -> in-loop vmem is exactly 8 ops/tile, vmcnt(8) spans tile
// t+1's batch.  Mask loaded raw, scaled by log2e at the cur<-nxt copy.
// LDS 32 KB declared -> >=3 blocks/CU by LDS; launch_bounds(256,3) keeps
// VGPR <= 170 (3 waves/SIMD).  768 = 3x256: zero-tail single round.
struct AttnArgs {
  const unsigned short* q[2];
  const unsigned short* k[2];
  const unsigned short* vt[2];
  const float* mask[2];
  unsigned short* ctx[2];
};

__global__ __launch_bounds__(256, 3)
void attn_kernel(AttnArgs args) {
  const int z = blockIdx.z;
  const int b = z >> 1, w = z & 1;
  const int h = blockIdx.y;
  const int q0 = blockIdx.x * 256;

  const unsigned short* __restrict__ Q  = args.q[1 - w];  // ctx1 <- q2, ctx2 <- q1
  const unsigned short* __restrict__ K  = args.k[w];
  const unsigned short* __restrict__ Vt = args.vt[w] + ((size_t)(b * 12 + h)) * 64 * 2048;
  const float* __restrict__ mask = args.mask[w] + (size_t)b * SS;
  unsigned short* __restrict__ O = args.ctx[w];

  __shared__ __align__(16) unsigned short kv_sh[2][8192];   // 32 KB total

  const int tid  = threadIdx.x;
  const int lane = tid & 63;
  const int wave = tid >> 6;
  const int l15 = lane & 15;
  const int lq  = lane >> 4;   // 0..3
  const int rsw = (l15 >> 1) & 3;            // row-derived swizzle term for frag reads
  const int swK = (lq ^ rsw) * 8;            // K-frag block offset (one b128)

  const float SCL2 = 0.125f * 1.4426950408889634f;  // /sqrt(64) * log2(e)
  const float L2E  = 1.4426950408889634f;

  const unsigned short* gbase;
  int gadv;
  int goff[4];
  {
    const int rl = lane >> 2;                  // row_local 0..15
    const int jb = (lane & 3) ^ ((lane >> 3) & 3);
    if (wave < 2) {
      gbase = K + (size_t)(b * SS) * 768 + h * 64 + (wave & 1) * 32;
      gadv  = 64 * 768;
      #pragma unroll
      for (int j = 0; j < 4; ++j) goff[j] = (j * 16 + rl) * 768 + jb * 8;
    } else {
      gbase = Vt + (wave & 1) * 32;
      gadv  = 64;
      #pragma unroll
      for (int j = 0; j < 4; ++j) goff[j] = (j * 16 + rl) * 2048 + jb * 8;
    }
  }

  // Q fragments: rows q0 + wave*64 + mt*16 + l15, k = ks*32 + lq*8 + j
  short8 qf[4][2];
  #pragma unroll
  for (int mt = 0; mt < 4; ++mt) {
    const size_t qrow = (size_t)(b * SS + q0 + wave * 64 + mt * 16 + l15) * 768 + h * 64;
    qf[mt][0] = *(const short8*)(Q + qrow + lq * 8);
    qf[mt][1] = *(const short8*)(Q + qrow + 32 + lq * 8);
  }

  // O^T accumulator: oaccT[mt][ntd][r] = O[q = mt*16+l15][d = ntd*16 + lq*4 + r]
  floatx4 oaccT[4][4];
  #pragma unroll
  for (int mt = 0; mt < 4; ++mt)
    #pragma unroll
    for (int nt = 0; nt < 4; ++nt) { floatx4 zz = {0.f,0.f,0.f,0.f}; oaccT[mt][nt] = zz; }
  float lad[4];
  #pragma unroll
  for (int mt = 0; mt < 4; ++mt) lad[mt] = 0.f;

  // prologue: mask for tile 0 (raw), scale by log2e, then stage tile 0 K/V
  float4 mk_cur[4], mk_nxt[4];
  #pragma unroll
  for (int nt = 0; nt < 4; ++nt) mk_cur[nt] = *(const float4*)(mask + nt * 16 + lq * 4);
  #pragma unroll
  for (int nt = 0; nt < 4; ++nt) {
    mk_cur[nt].x *= L2E; mk_cur[nt].y *= L2E;
    mk_cur[nt].z *= L2E; mk_cur[nt].w *= L2E;
  }
  #pragma unroll
  for (int j = 0; j < 4; ++j)
    gload_lds16(gbase + goff[j], &kv_sh[0][0] + (wave * 4 + j) * 512);
  gbase += gadv;

  const int NT = SS / 64;

  for (int t = 0; t < NT; ++t) {
    const int cb = t & 1;
    // prefetch tile t+1: mask loads FIRST so vmcnt(8) spans exactly the
    // 8 vmem ops (4 mask + 4 stage) of tile t+1 — round-1-proven pattern.
    if (t + 1 < NT) {
      const int kt1 = (t + 1) * 64;
      #pragma unroll
      for (int nt = 0; nt < 4; ++nt)
        mk_nxt[nt] = *(const float4*)(mask + kt1 + nt * 16 + lq * 4);
      #pragma unroll
      for (int j = 0; j < 4; ++j)
        gload_lds16(gbase + goff[j], &kv_sh[cb ^ 1][0] + (wave * 4 + j) * 512);
      gbase += gadv;
      asm volatile("s_waitcnt vmcnt(8)" ::: "memory");
    } else {
      asm volatile("s_waitcnt vmcnt(0)" ::: "memory");
    }
    __builtin_amdgcn_s_barrier();
    asm volatile("" ::: "memory");
    __builtin_amdgcn_s_setprio(1);

    const unsigned short* kb = &kv_sh[cb][0];
    const unsigned short* vb = &kv_sh[cb][4096];

    #pragma unroll
    for (int ksh = 0; ksh < 2; ++ksh) {       // 32-key half
      // V pieces (V^T[d][k], 4 consecutive keys per lane) for this half
      uintx2 vf[2][4];
      #pragma unroll
      for (int ntk = 0; ntk < 2; ++ntk) {
        const int blk = ((ntk * 2 + (lq >> 1)) ^ rsw) * 8 + (lq & 1) * 4;
        #pragma unroll
        for (int ntd = 0; ntd < 4; ++ntd)
          vf[ntk][ntd] = *(const uintx2*)(vb + ksh * 2048 + (ntd * 16 + l15) * 32 + blk);
      }

      // QK^T (swapped: S^T = K x Q^T) + softmax, P kept in registers
      uintx2 pk[4][2];
      #pragma unroll
      for (int ntk = 0; ntk < 2; ++ntk) {
        const int nt = ksh * 2 + ntk;
        const int ro = (nt * 16 + l15) * 32 + swK;
        const short8 kf0 = *(const short8*)(kb + ro);
        const short8 kf1 = *(const short8*)(kb + 2048 + ro);
        #pragma unroll
        for (int mt = 0; mt < 4; ++mt) {
          floatx4 zz = {0.f,0.f,0.f,0.f};
          floatx4 sacc = __builtin_amdgcn_mfma_f32_16x16x32_bf16(kf0, qf[mt][0], zz, 0, 0, 0);
          sacc = __builtin_amdgcn_mfma_f32_16x16x32_bf16(kf1, qf[mt][1], sacc, 0, 0, 0);
          // lane holds q = mt*16 + l15, keys nt*16 + lq*4 + {0..3}
          const float p0 = __builtin_amdgcn_exp2f(sacc[0] * SCL2 + mk_cur[nt].x);
          const float p1 = __builtin_amdgcn_exp2f(sacc[1] * SCL2 + mk_cur[nt].y);
          const float p2 = __builtin_amdgcn_exp2f(sacc[2] * SCL2 + mk_cur[nt].z);
          const float p3 = __builtin_amdgcn_exp2f(sacc[3] * SCL2 + mk_cur[nt].w);
          lad[mt] += (p0 + p1) + (p2 + p3);
          pk[mt][ntk].x = cvt_pk_bf16(p0, p1);   // k-slots lq*4+{0,1} of group ntk
          pk[mt][ntk].y = cvt_pk_bf16(p2, p3);   // k-slots lq*4+{2,3}
        }
      }

      // PV in-register, K=32: O^T[d][q] += V^T * P, one MFMA per (mt,ntd).
      #pragma unroll
      for (int mt = 0; mt < 4; ++mt) {
        const short8 pb8 = cat64(pk[mt][0], pk[mt][1]);
        #pragma unroll
        for (int ntd = 0; ntd < 4; ++ntd) {
          const short8 va8 = cat64(vf[0][ntd], vf[1][ntd]);
          oaccT[mt][ntd] = __builtin_amdgcn_mfma_f32_16x16x32_bf16(va8, pb8, oaccT[mt][ntd], 0, 0, 0);
        }
      }
    }

    __builtin_amdgcn_s_setprio(0);
    asm volatile("" ::: "memory");
    __builtin_amdgcn_s_barrier();   // protect kv buf reuse two tiles later
    asm volatile("" ::: "memory");

    // promote next tile's mask (scale by log2e here; loads landed during
    // the compute phase, dependency wait is ~free at this point)
    #pragma unroll
    for (int nt = 0; nt < 4; ++nt) {
      mk_cur[nt].x = mk_nxt[nt].x * L2E;
      mk_cur[nt].y = mk_nxt[nt].y * L2E;
      mk_cur[nt].z = mk_nxt[nt].z * L2E;
      mk_cur[nt].w = mk_nxt[nt].w * L2E;
    }
  }

  // epilogue: lane holds full O-row slice for q = mt*16 + l15 (cols lq*4+r);
  // lad[mt] partial over this lane's key groups -> 2 shuffles for the full sum.
  #pragma unroll
  for (int mt = 0; mt < 4; ++mt) {
    float ls = lad[mt];
    ls += __shfl_xor(ls, 16);
    ls += __shfl_xor(ls, 32);
    const float inv = 1.f / ls;
    const int gq = q0 + wave * 64 + mt * 16 + l15;
    unsigned short* orow = O + (size_t)(b * SS + gq) * 768 + h * 64 + lq * 4;
    #pragma unroll
    for (int ntd = 0; ntd < 4; ++ntd) {
      uintx2 o2;
      o2.x = cvt_pk_bf16(oaccT[mt][ntd][0] * inv, oaccT[mt][ntd][1] * inv);
      o2.y = cvt_pk_bf16(oaccT[mt][ntd][2] * inv, oaccT[mt][ntd][3] * inv);
      *(uintx2*)(orow + ntd * 16) = o2;
    }
  }
}

// ---------------------------------------------------------------- layernorm (one block per row, both streams)
// reads the pre-LN activation as bf16 (written by gemm<1>), math in fp32
struct LnArgs { const unsigned short* src[2]; const float* g[2]; const float* bta[2]; float* out[2]; };

__global__ __launch_bounds__(256)
void ln_kernel(LnArgs a) {
  const int z = blockIdx.y;
  const int row = blockIdx.x;
  const int tid = threadIdx.x;
  const unsigned short* x = a.src[z] + (size_t)row * 768;
  const float* g = a.g[z];
  const float* bta = a.bta[z];
  const float v0 = bf2f(x[tid]), v1 = bf2f(x[tid + 256]), v2 = bf2f(x[tid + 512]);
  float sum = v0 + v1 + v2;
  float sq  = v0 * v0 + v1 * v1 + v2 * v2;
  #pragma unroll
  for (int d = 1; d < 64; d <<= 1) {
    sum += __shfl_xor(sum, d, 64);
    sq  += __shfl_xor(sq, d, 64);
  }
  __shared__ float ssum[4], ssq[4];
  const int wave = tid >> 6, lane = tid & 63;
  if (lane == 0) { ssum[wave] = sum; ssq[wave] = sq; }
  __syncthreads();
  sum = ssum[0] + ssum[1] + ssum[2] + ssum[3];
  sq  = ssq[0] + ssq[1] + ssq[2] + ssq[3];
  const float mean = sum * (1.f / 768.f);
  const float var  = sq * (1.f / 768.f) - mean * mean;
  const float rs   = rsqrtf(var + 1e-12f);
  float* o = a.out[z] + (size_t)row * 768;
  o[tid]       = (v0 - mean) * rs * g[tid]       + bta[tid];
  o[tid + 256] = (v1 - mean) * rs * g[tid + 256] + bta[tid + 256];
  o[tid + 512] = (v2 - mean) * rs * g[tid + 512] + bta[tid + 512];
}

// ---------------------------------------------------------------- launch
extern "C" void kernel_launch(void* const* d_in, const int* in_sizes, int n_in,
                              void* d_out, int out_size, void* d_ws, size_t ws_size,
                              hipStream_t stream) {
  const float* x1    = (const float*)d_in[0];
  const float* mask1 = (const float*)d_in[1];
  const float* x2    = (const float*)d_in[2];
  const float* mask2 = (const float*)d_in[3];

  char* ws = (char*)d_ws;
  const size_t SZ_X = (size_t)MR * HID_ * 2;     // bf16 [8192,768] = 12,582,912 B
  const size_t SZ_W = (size_t)HID_ * HID_ * 2;   // bf16 [768,768]

  unsigned short* xb0 = (unsigned short*)(ws);
  unsigned short* xb1 = (unsigned short*)(ws + SZ_X);
  unsigned short* wtb[8];
  for (int i = 0; i < 8; ++i) wtb[i] = (unsigned short*)(ws + 2 * SZ_X + i * SZ_W);
  char* qbase = ws + 2 * SZ_X + 8 * SZ_W;
  unsigned short* qkvb[6];
  for (int i = 0; i < 6; ++i) qkvb[i] = (unsigned short*)(qbase + i * SZ_X);
  unsigned short* ctxb[2];
  ctxb[0] = (unsigned short*)(qbase + 6 * SZ_X);
  ctxb[1] = (unsigned short*)(qbase + 7 * SZ_X);
  // pre-LN bf16 buffers alias qkv[0..1] (dead after attention)
  unsigned short* projb[2];
  projb[0] = (unsigned short*)(qbase);
  projb[1] = (unsigned short*)(qbase + SZ_X);

  // 1. cast inputs to bf16 (both streams, one launch)
  CastArgs ca;
  ca.src[0] = x1; ca.src[1] = x2; ca.dst[0] = xb0; ca.dst[1] = xb1;
  cast_kernel<<<dim3(XELEMS / 1024, 2), 256, 0, stream>>>(ca);

  // 2. transpose+cast weights (q1,k1,v1,q2,k2,v2,d1,d2 at d_in[4+2z])
  WArgs wa;
  for (int z = 0; z < 8; ++z) { wa.src[z] = (const float*)d_in[4 + 2 * z]; wa.dst[z] = wtb[z]; }
  wcast_kernel<<<dim3(24, 24, 8), 256, 0, stream>>>(wa);

  // 3. QKV projections (6 GEMMs batched in grid.z); V outputs written transposed
  GemmArgs ga = {};
  for (int z = 0; z < 6; ++z) {
    ga.A[z]    = (z < 3) ? xb0 : xb1;
    ga.Bt[z]   = wtb[z];
    ga.bias[z] = (const float*)d_in[5 + 2 * z];
    ga.outb[z] = qkvb[z];
    ga.tmode[z] = (z == 2 || z == 5) ? 2 : 0;
  }
  gemm_kernel<0><<<dim3(64, 6, 6), 256, 0, stream>>>(ga);

  // 4. bidirectional cross attention (Q-tile 256, 64 q/wave)
  AttnArgs aa;
  aa.q[0] = qkvb[0]; aa.q[1] = qkvb[3];
  aa.k[0] = qkvb[1]; aa.k[1] = qkvb[4];
  aa.vt[0] = qkvb[2]; aa.vt[1] = qkvb[5];
  aa.mask[0] = mask1; aa.mask[1] = mask2;
  aa.ctx[0] = ctxb[0]; aa.ctx[1] = ctxb[1];
  attn_kernel<<<dim3(8, 12, 8), 256, 0, stream>>>(aa);

  // 5. output projection + bias + residual -> bf16 pre-LN activation
  GemmArgs gp = {};
  for (int w = 0; w < 2; ++w) {
    gp.A[w]     = ctxb[w];
    gp.Bt[w]    = wtb[6 + w];
    gp.bias[w]  = (const float*)d_in[17 + 2 * w];
    gp.resid[w] = (w == 0) ? x1 : x2;
    gp.outb[w]  = projb[w];
  }
  gemm_kernel<1><<<dim3(64, 6, 2), 256, 0, stream>>>(gp);

  // 6. layernorm -> d_out (h1 then h2, one launch)
  float* out = (float*)d_out;
  LnArgs la;
  la.src[0] = projb[0]; la.src[1] = projb[1];
  la.g[0] = (const float*)d_in[20]; la.bta[0] = (const float*)d_in[21];
  la.g[1] = (const float*)d_in[22]; la.bta[1] = (const float*)d_in[23];
  la.out[0] = out; la.out[1] = out + XELEMS;
  ln_kernel<<<dim3(MR, 2), 256, 0, stream>>>(la);
}

// Round 8
// 443.792 us; speedup vs baseline: 2.5079x; 2.5079x over previous
//
#include <hip/hip_runtime.h>
#include <hip/hip_bf16.h>

// Problem constants
#define BB   4
#define SS   2048
#define HID_ 768
#define NH   12
#define HD_  64
#define MR   8192          // B*S
#define XELEMS 6291456     // 8192*768

typedef __attribute__((ext_vector_type(8))) short short8;
typedef __attribute__((ext_vector_type(4))) float floatx4;
typedef __attribute__((ext_vector_type(2))) unsigned int uintx2;

__device__ __forceinline__ unsigned short f2bf(float f) {
  union { float f; unsigned int u; } x; x.f = f;
  unsigned int r = x.u + 0x7fffu + ((x.u >> 16) & 1u);  // RNE
  return (unsigned short)(r >> 16);
}

__device__ __forceinline__ float bf2f(unsigned short u) {
  return __builtin_bit_cast(float, (unsigned int)u << 16);
}

// packed f32x2 -> bf16x2 (RNE), 1 VALU instr for 2 values
__device__ __forceinline__ unsigned int cvt_pk_bf16(float lo, float hi) {
  unsigned int r;
  asm("v_cvt_pk_bf16_f32 %0, %1, %2" : "=v"(r) : "v"(lo), "v"(hi));
  return r;
}

// concat two 4-key b64 pieces into one 8-slot MFMA operand (regs j0..3 | j4..7)
__device__ __forceinline__ short8 cat64(uintx2 a, uintx2 b) {
  union { unsigned int u[4]; short8 s; } x;
  x.u[0] = a.x; x.u[1] = a.y; x.u[2] = b.x; x.u[3] = b.y;
  return x.s;
}

// async global -> LDS, 16 B per lane; lds base is wave-uniform, HW adds lane*16
__device__ __forceinline__ void gload_lds16(const unsigned short* g, unsigned short* l) {
  __builtin_amdgcn_global_load_lds(
      (const __attribute__((address_space(1))) unsigned int*)g,
      (__attribute__((address_space(3))) unsigned int*)l, 16, 0, 0);
}

// ---------------------------------------------------------------- cast fp32 -> bf16 (both streams)
struct CastArgs { const float* src[2]; unsigned short* dst[2]; };

__global__ __launch_bounds__(256)
void cast_kernel(CastArgs a) {
  const int z = blockIdx.y;
  int i = (blockIdx.x * 256 + threadIdx.x) * 4;
  float4 v = *(const float4*)(a.src[z] + i);
  ushort4 o;
  o.x = f2bf(v.x); o.y = f2bf(v.y); o.z = f2bf(v.z); o.w = f2bf(v.w);
  *(ushort4*)(a.dst[z] + i) = o;
}

// ---------------------------------------------------------------- weight transpose+cast
// in: W[k][n] fp32 (768x768), out: Wt[n][k] bf16
struct WArgs { const float* src[8]; unsigned short* dst[8]; };

__global__ __launch_bounds__(256)
void wcast_kernel(WArgs args) {
  __shared__ float tile[32][33];
  const int w = blockIdx.z;
  const float* __restrict__ src = args.src[w];
  unsigned short* __restrict__ dst = args.dst[w];
  const int n0 = blockIdx.x * 32, k0 = blockIdx.y * 32;
  const int tx = threadIdx.x & 31, ty = threadIdx.x >> 5;  // 32 x 8
  #pragma unroll
  for (int i = 0; i < 4; ++i)
    tile[ty + 8 * i][tx] = src[(size_t)(k0 + ty + 8 * i) * HID_ + n0 + tx];
  __syncthreads();
  #pragma unroll
  for (int i = 0; i < 4; ++i)
    dst[(size_t)(n0 + ty + 8 * i) * HID_ + k0 + tx] = f2bf(tile[tx][ty + 8 * i]);
}

// ---------------------------------------------------------------- GEMM: C = A[M,768] * Bt[N,768]^T
// ROUND-3-EXACT single-buffered loop (verified passing): per K-step
// { stage cur ; __syncthreads ; ds_read+MFMA ; __syncthreads }.
// FROZEN: dbuf variants (r4 counted vmcnt / r5 drain) both failed — do not
// re-pipeline this loop without a new verification path.
// MODE 0: bf16 out; per-z tmode 0 = row-major [tok][hid], 2 = V-transposed [b,h,d,s]
// MODE 1: bf16 out = acc + bias + resid  (pre-LN activation, read by ln_kernel)
struct GemmArgs {
  const unsigned short* A[6];
  const unsigned short* Bt[6];
  const float* bias[6];
  const float* resid[6];
  unsigned short* outb[6];
  int tmode[6];
};

template <int MODE>
__global__ __launch_bounds__(256)
void gemm_kernel(GemmArgs args) {
  const int z = blockIdx.z;
  const unsigned short* __restrict__ A  = args.A[z];
  const unsigned short* __restrict__ Bt = args.Bt[z];
  const int m0 = blockIdx.x * 128;
  const int n0 = blockIdx.y * 128;

  __shared__ __align__(16) unsigned short a_sh[128 * 32];  // 8 KB, pitch 32
  __shared__ __align__(16) unsigned short b_sh[128 * 32];

  const int tid  = threadIdx.x;
  const int lane = tid & 63;
  const int wave = tid >> 6;
  const int wm = (wave & 1) * 64;
  const int wn = (wave >> 1) * 64;
  const int l15 = lane & 15;
  const int ko  = lane >> 4;     // 0..3

  floatx4 acc[4][4];
  #pragma unroll
  for (int mt = 0; mt < 4; ++mt)
    #pragma unroll
    for (int nt = 0; nt < 4; ++nt) {
      floatx4 zz = {0.f, 0.f, 0.f, 0.f};
      acc[mt][nt] = zz;
    }

  // staging: 8 chunks of 16 rows x 32 cols; wave handles chunks {2w, 2w+1}
  const int ch0 = wave * 2;
  size_t aoff[2], boff[2];
  unsigned short *adst[2], *bdst[2];
  #pragma unroll
  for (int j = 0; j < 2; ++j) {
    const int ch = ch0 + j;
    const int row = ch * 16 + (lane >> 2);
    const int col = (lane & 3) * 8;
    aoff[j] = (size_t)(m0 + row) * 768 + col;
    boff[j] = (size_t)(n0 + row) * 768 + col;
    adst[j] = a_sh + ch * 512 + lane * 8;
    bdst[j] = b_sh + ch * 512 + lane * 8;
  }

  for (int k0 = 0; k0 < 768; k0 += 32) {
    #pragma unroll
    for (int j = 0; j < 2; ++j) {
      gload_lds16(A  + aoff[j] + k0, adst[j]);
      gload_lds16(Bt + boff[j] + k0, bdst[j]);
    }
    __syncthreads();
    short8 af[4], bfr[4];
    #pragma unroll
    for (int t = 0; t < 4; ++t) {
      af[t]  = *(const short8*)(a_sh + (wm + t * 16 + l15) * 32 + ko * 8);
      bfr[t] = *(const short8*)(b_sh + (wn + t * 16 + l15) * 32 + ko * 8);
    }
    #pragma unroll
    for (int mt = 0; mt < 4; ++mt)
      #pragma unroll
      for (int nt = 0; nt < 4; ++nt)
        acc[mt][nt] = __builtin_amdgcn_mfma_f32_16x16x32_bf16(af[mt], bfr[nt], acc[mt][nt], 0, 0, 0);
    __syncthreads();
  }

  // epilogue. C/D layout: row = (lane>>4)*4 + r, col = lane&15
  if (MODE == 0) {
    const float* __restrict__ bias = args.bias[z];
    unsigned short* __restrict__ out = args.outb[z];
    if (args.tmode[z] == 0) {
      #pragma unroll
      for (int mt = 0; mt < 4; ++mt) {
        const int gm = m0 + wm + mt * 16 + ko * 4;
        #pragma unroll
        for (int nt = 0; nt < 4; ++nt) {
          const int gn = n0 + wn + nt * 16 + l15;
          const float bv = bias[gn];
          #pragma unroll
          for (int r = 0; r < 4; ++r)
            out[(size_t)(gm + r) * 768 + gn] = f2bf(acc[mt][nt][r] + bv);
        }
      }
    } else {
      // V: write transposed [b][h][d][s]; r walks consecutive s -> ushort4 stores
      #pragma unroll
      for (int mt = 0; mt < 4; ++mt) {
        const int gm = m0 + wm + mt * 16 + ko * 4;
        const int bb_ = gm >> 11;
        const int s   = gm & 2047;
        #pragma unroll
        for (int nt = 0; nt < 4; ++nt) {
          const int gn = n0 + wn + nt * 16 + l15;
          const float bv = bias[gn];
          const int h = gn >> 6, d = gn & 63;
          ushort4 o4;
          o4.x = f2bf(acc[mt][nt][0] + bv);
          o4.y = f2bf(acc[mt][nt][1] + bv);
          o4.z = f2bf(acc[mt][nt][2] + bv);
          o4.w = f2bf(acc[mt][nt][3] + bv);
          *(ushort4*)(out + ((size_t)((bb_ * 12 + h) * 64 + d)) * 2048 + s) = o4;
        }
      }
    }
  } else {
    // MODE 1: pre-LN activation = acc + bias + resid, stored bf16
    const float* __restrict__ bias  = args.bias[z];
    const float* __restrict__ resid = args.resid[z];
    unsigned short* __restrict__ out = args.outb[z];
    #pragma unroll
    for (int mt = 0; mt < 4; ++mt) {
      const int gm = m0 + wm + mt * 16 + ko * 4;
      #pragma unroll
      for (int nt = 0; nt < 4; ++nt) {
        const int gn = n0 + wn + nt * 16 + l15;
        const float bv = bias[gn];
        #pragma unroll
        for (int r = 0; r < 4; ++r)
          out[(size_t)(gm + r) * 768 + gn] =
              f2bf(acc[mt][nt][r] + bv + resid[(size_t)(gm + r) * 768 + gn]);
      }
    }
  }
}

// ---------------------------------------------------------------- flash attention
// grid: (S/256, H, B*2) = 768 blocks = exactly 3/CU.  z = b*2 + w.
// 64 q-rows PER WAVE.  K-tile 64 in 32-key halves.  Double-buffered K/V
// staging via global_load_lds.  Swapped QK^T -> S^T; PV fully in-register
// with K=32 MFMA (concat'd V/P pieces, identical k-slot perm).
// LDS block placement pos = kb ^ ((row>>1)&3).  s_setprio(1) around compute.
// LDS = 32 KB (mask in register double-buffer, r1-proven vmcnt(8) pattern:
// per tile 4 mask float4 loads FIRST then 4 staging loads = exactly 8 vmem).
// launch_bounds(256,2): r7's (256,3) forced massive scratch spills (VGPR 84,
// 1.97 GB scratch writes, attn 765us) — EXACTLY the failure documented in the
// r0 comment.  (256,2) lets regalloc sit at its natural ~130-140; 3 blocks/CU
// remain feasible (3x~140 <= 512 VGPR/SIMD, 3x32KB <= 160KB LDS).
struct AttnArgs {
  const unsigned short* q[2];
  const unsigned short* k[2];
  const unsigned short* vt[2];
  const float* mask[2];
  unsigned short* ctx[2];
};

__global__ __launch_bounds__(256, 2)
void attn_kernel(AttnArgs args) {
  const int z = blockIdx.z;
  const int b = z >> 1, w = z & 1;
  const int h = blockIdx.y;
  const int q0 = blockIdx.x * 256;

  const unsigned short* __restrict__ Q  = args.q[1 - w];  // ctx1 <- q2, ctx2 <- q1
  const unsigned short* __restrict__ K  = args.k[w];
  const unsigned short* __restrict__ Vt = args.vt[w] + ((size_t)(b * 12 + h)) * 64 * 2048;
  const float* __restrict__ mask = args.mask[w] + (size_t)b * SS;
  unsigned short* __restrict__ O = args.ctx[w];

  __shared__ __align__(16) unsigned short kv_sh[2][8192];   // 32 KB total

  const int tid  = threadIdx.x;
  const int lane = tid & 63;
  const int wave = tid >> 6;
  const int l15 = lane & 15;
  const int lq  = lane >> 4;   // 0..3
  const int rsw = (l15 >> 1) & 3;            // row-derived swizzle term for frag reads
  const int swK = (lq ^ rsw) * 8;            // K-frag block offset (one b128)

  const float SCL2 = 0.125f * 1.4426950408889634f;  // /sqrt(64) * log2(e)
  const float L2E  = 1.4426950408889634f;

  const unsigned short* gbase;
  int gadv;
  int goff[4];
  {
    const int rl = lane >> 2;                  // row_local 0..15
    const int jb = (lane & 3) ^ ((lane >> 3) & 3);
    if (wave < 2) {
      gbase = K + (size_t)(b * SS) * 768 + h * 64 + (wave & 1) * 32;
      gadv  = 64 * 768;
      #pragma unroll
      for (int j = 0; j < 4; ++j) goff[j] = (j * 16 + rl) * 768 + jb * 8;
    } else {
      gbase = Vt + (wave & 1) * 32;
      gadv  = 64;
      #pragma unroll
      for (int j = 0; j < 4; ++j) goff[j] = (j * 16 + rl) * 2048 + jb * 8;
    }
  }

  // Q fragments: rows q0 + wave*64 + mt*16 + l15, k = ks*32 + lq*8 + j
  short8 qf[4][2];
  #pragma unroll
  for (int mt = 0; mt < 4; ++mt) {
    const size_t qrow = (size_t)(b * SS + q0 + wave * 64 + mt * 16 + l15) * 768 + h * 64;
    qf[mt][0] = *(const short8*)(Q + qrow + lq * 8);
    qf[mt][1] = *(const short8*)(Q + qrow + 32 + lq * 8);
  }

  // O^T accumulator: oaccT[mt][ntd][r] = O[q = mt*16+l15][d = ntd*16 + lq*4 + r]
  floatx4 oaccT[4][4];
  #pragma unroll
  for (int mt = 0; mt < 4; ++mt)
    #pragma unroll
    for (int nt = 0; nt < 4; ++nt) { floatx4 zz = {0.f,0.f,0.f,0.f}; oaccT[mt][nt] = zz; }
  float lad[4];
  #pragma unroll
  for (int mt = 0; mt < 4; ++mt) lad[mt] = 0.f;

  // prologue: mask for tile 0 (raw), scale by log2e, then stage tile 0 K/V
  float4 mk_cur[4], mk_nxt[4];
  #pragma unroll
  for (int nt = 0; nt < 4; ++nt) mk_cur[nt] = *(const float4*)(mask + nt * 16 + lq * 4);
  #pragma unroll
  for (int nt = 0; nt < 4; ++nt) {
    mk_cur[nt].x *= L2E; mk_cur[nt].y *= L2E;
    mk_cur[nt].z *= L2E; mk_cur[nt].w *= L2E;
  }
  #pragma unroll
  for (int j = 0; j < 4; ++j)
    gload_lds16(gbase + goff[j], &kv_sh[0][0] + (wave * 4 + j) * 512);
  gbase += gadv;

  const int NT = SS / 64;

  for (int t = 0; t < NT; ++t) {
    const int cb = t & 1;
    // prefetch tile t+1: mask loads FIRST so vmcnt(8) spans exactly the
    // 8 vmem ops (4 mask + 4 stage) of tile t+1 — round-1-proven pattern.
    if (t + 1 < NT) {
      const int kt1 = (t + 1) * 64;
      #pragma unroll
      for (int nt = 0; nt < 4; ++nt)
        mk_nxt[nt] = *(const float4*)(mask + kt1 + nt * 16 + lq * 4);
      #pragma unroll
      for (int j = 0; j < 4; ++j)
        gload_lds16(gbase + goff[j], &kv_sh[cb ^ 1][0] + (wave * 4 + j) * 512);
      gbase += gadv;
      asm volatile("s_waitcnt vmcnt(8)" ::: "memory");
    } else {
      asm volatile("s_waitcnt vmcnt(0)" ::: "memory");
    }
    __builtin_amdgcn_s_barrier();
    asm volatile("" ::: "memory");
    __builtin_amdgcn_s_setprio(1);

    const unsigned short* kb = &kv_sh[cb][0];
    const unsigned short* vb = &kv_sh[cb][4096];

    #pragma unroll
    for (int ksh = 0; ksh < 2; ++ksh) {       // 32-key half
      // V pieces (V^T[d][k], 4 consecutive keys per lane) for this half
      uintx2 vf[2][4];
      #pragma unroll
      for (int ntk = 0; ntk < 2; ++ntk) {
        const int blk = ((ntk * 2 + (lq >> 1)) ^ rsw) * 8 + (lq & 1) * 4;
        #pragma unroll
        for (int ntd = 0; ntd < 4; ++ntd)
          vf[ntk][ntd] = *(const uintx2*)(vb + ksh * 2048 + (ntd * 16 + l15) * 32 + blk);
      }

      // QK^T (swapped: S^T = K x Q^T) + softmax, P kept in registers
      uintx2 pk[4][2];
      #pragma unroll
      for (int ntk = 0; ntk < 2; ++ntk) {
        const int nt = ksh * 2 + ntk;
        const int ro = (nt * 16 + l15) * 32 + swK;
        const short8 kf0 = *(const short8*)(kb + ro);
        const short8 kf1 = *(const short8*)(kb + 2048 + ro);
        #pragma unroll
        for (int mt = 0; mt < 4; ++mt) {
          floatx4 zz = {0.f,0.f,0.f,0.f};
          floatx4 sacc = __builtin_amdgcn_mfma_f32_16x16x32_bf16(kf0, qf[mt][0], zz, 0, 0, 0);
          sacc = __builtin_amdgcn_mfma_f32_16x16x32_bf16(kf1, qf[mt][1], sacc, 0, 0, 0);
          // lane holds q = mt*16 + l15, keys nt*16 + lq*4 + {0..3}
          const float p0 = __builtin_amdgcn_exp2f(sacc[0] * SCL2 + mk_cur[nt].x);
          const float p1 = __builtin_amdgcn_exp2f(sacc[1] * SCL2 + mk_cur[nt].y);
          const float p2 = __builtin_amdgcn_exp2f(sacc[2] * SCL2 + mk_cur[nt].z);
          const float p3 = __builtin_amdgcn_exp2f(sacc[3] * SCL2 + mk_cur[nt].w);
          lad[mt] += (p0 + p1) + (p2 + p3);
          pk[mt][ntk].x = cvt_pk_bf16(p0, p1);   // k-slots lq*4+{0,1} of group ntk
          pk[mt][ntk].y = cvt_pk_bf16(p2, p3);   // k-slots lq*4+{2,3}
        }
      }

      // PV in-register, K=32: O^T[d][q] += V^T * P, one MFMA per (mt,ntd).
      #pragma unroll
      for (int mt = 0; mt < 4; ++mt) {
        const short8 pb8 = cat64(pk[mt][0], pk[mt][1]);
        #pragma unroll
        for (int ntd = 0; ntd < 4; ++ntd) {
          const short8 va8 = cat64(vf[0][ntd], vf[1][ntd]);
          oaccT[mt][ntd] = __builtin_amdgcn_mfma_f32_16x16x32_bf16(va8, pb8, oaccT[mt][ntd], 0, 0, 0);
        }
      }
    }

    __builtin_amdgcn_s_setprio(0);
    asm volatile("" ::: "memory");
    __builtin_amdgcn_s_barrier();   // protect kv buf reuse two tiles later
    asm volatile("" ::: "memory");

    // promote next tile's mask (scale by log2e here; loads landed during
    // the compute phase, dependency wait is ~free at this point)
    #pragma unroll
    for (int nt = 0; nt < 4; ++nt) {
      mk_cur[nt].x = mk_nxt[nt].x * L2E;
      mk_cur[nt].y = mk_nxt[nt].y * L2E;
      mk_cur[nt].z = mk_nxt[nt].z * L2E;
      mk_cur[nt].w = mk_nxt[nt].w * L2E;
    }
  }

  // epilogue: lane holds full O-row slice for q = mt*16 + l15 (cols lq*4+r);
  // lad[mt] partial over this lane's key groups -> 2 shuffles for the full sum.
  #pragma unroll
  for (int mt = 0; mt < 4; ++mt) {
    float ls = lad[mt];
    ls += __shfl_xor(ls, 16);
    ls += __shfl_xor(ls, 32);
    const float inv = 1.f / ls;
    const int gq = q0 + wave * 64 + mt * 16 + l15;
    unsigned short* orow = O + (size_t)(b * SS + gq) * 768 + h * 64 + lq * 4;
    #pragma unroll
    for (int ntd = 0; ntd < 4; ++ntd) {
      uintx2 o2;
      o2.x = cvt_pk_bf16(oaccT[mt][ntd][0] * inv, oaccT[mt][ntd][1] * inv);
      o2.y = cvt_pk_bf16(oaccT[mt][ntd][2] * inv, oaccT[mt][ntd][3] * inv);
      *(uintx2*)(orow + ntd * 16) = o2;
    }
  }
}

// ---------------------------------------------------------------- layernorm (one block per row, both streams)
// reads the pre-LN activation as bf16 (written by gemm<1>), math in fp32
struct LnArgs { const unsigned short* src[2]; const float* g[2]; const float* bta[2]; float* out[2]; };

__global__ __launch_bounds__(256)
void ln_kernel(LnArgs a) {
  const int z = blockIdx.y;
  const int row = blockIdx.x;
  const int tid = threadIdx.x;
  const unsigned short* x = a.src[z] + (size_t)row * 768;
  const float* g = a.g[z];
  const float* bta = a.bta[z];
  const float v0 = bf2f(x[tid]), v1 = bf2f(x[tid + 256]), v2 = bf2f(x[tid + 512]);
  float sum = v0 + v1 + v2;
  float sq  = v0 * v0 + v1 * v1 + v2 * v2;
  #pragma unroll
  for (int d = 1; d < 64; d <<= 1) {
    sum += __shfl_xor(sum, d, 64);
    sq  += __shfl_xor(sq, d, 64);
  }
  __shared__ float ssum[4], ssq[4];
  const int wave = tid >> 6, lane = tid & 63;
  if (lane == 0) { ssum[wave] = sum; ssq[wave] = sq; }
  __syncthreads();
  sum = ssum[0] + ssum[1] + ssum[2] + ssum[3];
  sq  = ssq[0] + ssq[1] + ssq[2] + ssq[3];
  const float mean = sum * (1.f / 768.f);
  const float var  = sq * (1.f / 768.f) - mean * mean;
  const float rs   = rsqrtf(var + 1e-12f);
  float* o = a.out[z] + (size_t)row * 768;
  o[tid]       = (v0 - mean) * rs * g[tid]       + bta[tid];
  o[tid + 256] = (v1 - mean) * rs * g[tid + 256] + bta[tid + 256];
  o[tid + 512] = (v2 - mean) * rs * g[tid + 512] + bta[tid + 512];
}

// ---------------------------------------------------------------- launch
extern "C" void kernel_launch(void* const* d_in, const int* in_sizes, int n_in,
                              void* d_out, int out_size, void* d_ws, size_t ws_size,
                              hipStream_t stream) {
  const float* x1    = (const float*)d_in[0];
  const float* mask1 = (const float*)d_in[1];
  const float* x2    = (const float*)d_in[2];
  const float* mask2 = (const float*)d_in[3];

  char* ws = (char*)d_ws;
  const size_t SZ_X = (size_t)MR * HID_ * 2;     // bf16 [8192,768] = 12,582,912 B
  const size_t SZ_W = (size_t)HID_ * HID_ * 2;   // bf16 [768,768]

  unsigned short* xb0 = (unsigned short*)(ws);
  unsigned short* xb1 = (unsigned short*)(ws + SZ_X);
  unsigned short* wtb[8];
  for (int i = 0; i < 8; ++i) wtb[i] = (unsigned short*)(ws + 2 * SZ_X + i * SZ_W);
  char* qbase = ws + 2 * SZ_X + 8 * SZ_W;
  unsigned short* qkvb[6];
  for (int i = 0; i < 6; ++i) qkvb[i] = (unsigned short*)(qbase + i * SZ_X);
  unsigned short* ctxb[2];
  ctxb[0] = (unsigned short*)(qbase + 6 * SZ_X);
  ctxb[1] = (unsigned short*)(qbase + 7 * SZ_X);
  // pre-LN bf16 buffers alias qkv[0..1] (dead after attention)
  unsigned short* projb[2];
  projb[0] = (unsigned short*)(qbase);
  projb[1] = (unsigned short*)(qbase + SZ_X);

  // 1. cast inputs to bf16 (both streams, one launch)
  CastArgs ca;
  ca.src[0] = x1; ca.src[1] = x2; ca.dst[0] = xb0; ca.dst[1] = xb1;
  cast_kernel<<<dim3(XELEMS / 1024, 2), 256, 0, stream>>>(ca);

  // 2. transpose+cast weights (q1,k1,v1,q2,k2,v2,d1,d2 at d_in[4+2z])
  WArgs wa;
  for (int z = 0; z < 8; ++z) { wa.src[z] = (const float*)d_in[4 + 2 * z]; wa.dst[z] = wtb[z]; }
  wcast_kernel<<<dim3(24, 24, 8), 256, 0, stream>>>(wa);

  // 3. QKV projections (6 GEMMs batched in grid.z); V outputs written transposed
  GemmArgs ga = {};
  for (int z = 0; z < 6; ++z) {
    ga.A[z]    = (z < 3) ? xb0 : xb1;
    ga.Bt[z]   = wtb[z];
    ga.bias[z] = (const float*)d_in[5 + 2 * z];
    ga.outb[z] = qkvb[z];
    ga.tmode[z] = (z == 2 || z == 5) ? 2 : 0;
  }
  gemm_kernel<0><<<dim3(64, 6, 6), 256, 0, stream>>>(ga);

  // 4. bidirectional cross attention (Q-tile 256, 64 q/wave)
  AttnArgs aa;
  aa.q[0] = qkvb[0]; aa.q[1] = qkvb[3];
  aa.k[0] = qkvb[1]; aa.k[1] = qkvb[4];
  aa.vt[0] = qkvb[2]; aa.vt[1] = qkvb[5];
  aa.mask[0] = mask1; aa.mask[1] = mask2;
  aa.ctx[0] = ctxb[0]; aa.ctx[1] = ctxb[1];
  attn_kernel<<<dim3(8, 12, 8), 256, 0, stream>>>(aa);

  // 5. output projection + bias + residual -> bf16 pre-LN activation
  GemmArgs gp = {};
  for (int w = 0; w < 2; ++w) {
    gp.A[w]     = ctxb[w];
    gp.Bt[w]    = wtb[6 + w];
    gp.bias[w]  = (const float*)d_in[17 + 2 * w];
    gp.resid[w] = (w == 0) ? x1 : x2;
    gp.outb[w]  = projb[w];
  }
  gemm_kernel<1><<<dim3(64, 6, 2), 256, 0, stream>>>(gp);

  // 6. layernorm -> d_out (h1 then h2, one launch)
  float* out = (float*)d_out;
  LnArgs la;
  la.src[0] = projb[0]; la.src[1] = projb[1];
  la.g[0] = (const float*)d_in[20]; la.bta[0] = (const float*)d_in[21];
  la.g[1] = (const float*)d_in[22]; la.bta[1] = (const float*)d_in[23];
  la.out[0] = out; la.out[1] = out + XELEMS;
  ln_kernel<<<dim3(MR, 2), 256, 0, stream>>>(la);
}